// Round 5
// baseline (194.933 us; speedup 1.0000x reference)
//
#include <hip/hip_runtime.h>

// FAPELoss = fape + 0.05*clash + 0.3*physics -> single f32 scalar.
// Harness-fixed shapes: B=2, R=1024, A=4096, 19 vdw radii.
//
// Dispatches: hipMemsetAsync(4B ticket) + ONE fat kernel (last-block finalize).
// Block roles (grid = 1796):
//   [0,4):    stats (C/N counts + mask sum per batch; res_mask sums)
//   [4,1796): 7-block groups, r7<2 -> FAPE (512 blocks), r7>=2 -> pair (1280 blocks)
// FAPE is ATOM-major: each thread keeps NA=4 atoms in VGPRs for its whole life and
// loops RCH=16 frames whose 22 scalars arrive via uniform s_loads (SGPR broadcast).
// L2 traffic for FAPE drops ~117MB -> ~0.4MB vs frame-major. mask hoisted to the
// per-atom epilogue; res_mask folded into the accumulate fma.
// Pair: no LDS (j is wave-uniform -> scalar loads); clash counted via
// __popcll(__ballot(c)) -> SALU, no per-lane accumulation, no clash shuffle-reduce.
// Pair symmetry: each unordered pair evaluated once (band blocks weight i<j / i==j);
// pen adds both ordered CN terms via the uniform j-class select.
// (d > EPS) is vacuous: d >= sqrt(1e-12) = 1e-6 > 1e-8. Clash cmp uses d2 < mind^2.
//
// ws floats: [0](u32 ticket, memset 0) | fape_part[512] @4 | clash_part[1280] @516
//            | pen_part[1280] @1796 | stats[8] @3076
//            stats = [cC0,cN0,msum0, cC1,cN1,msum1, rsum0,rsum1]

constexpr int BB = 2;

constexpr int NA = 4;    // atoms per thread (FAPE)
constexpr int RCH = 16;  // frames per FAPE block
constexpr int NB_FAPE = 512;  // 8 atom-groups x 64 frame-chunks

constexpr int NI = 4;     // i-atoms per thread (pair)
constexpr int TJ = 16;    // j-tile
constexpr int IC = 1024;  // i-chunk
constexpr int NB_BAND = 512;
constexpr int NB_FULL = 768;
constexpr int NB_PAIR = NB_BAND + NB_FULL;

constexpr int NB_STAT = 4;
constexpr int NB_TOT = NB_STAT + NB_FAPE + NB_PAIR;  // 1796

__device__ __forceinline__ float wred(float v) {
#pragma unroll
  for (int o = 32; o > 0; o >>= 1) v += __shfl_down(v, o, 64);
  return v;
}
__device__ __forceinline__ double wredd(double v) {
#pragma unroll
  for (int o = 32; o > 0; o >>= 1) v += __shfl_down(v, o, 64);
  return v;
}

template <bool BAND>
__device__ __forceinline__ void pair_body(
    const float* __restrict__ coords, const int* __restrict__ types,
    const float* __restrict__ vdw, int A, int b, int ic, int jt, int tid,
    float& out_clash_wave, float& out_pen) {
  const int ibase = ic * IC;
  float xi[NI], yi[NI], zi[NI], qi[NI], ri[NI], cf[NI], nf[NI];
  int ii[NI];
#pragma unroll
  for (int k = 0; k < NI; ++k) {
    ii[k] = ibase + (k << 8) + tid;
    const size_t g = (size_t)b * A + ii[k];
    const float x = coords[g * 3], y = coords[g * 3 + 1], z = coords[g * 3 + 2];
    const int t = types[g];
    xi[k] = x; yi[k] = y; zi[k] = z;
    // match reference sq = ((x*x + y*y) + z*z) without fma contraction
    qi[k] = __fadd_rn(__fadd_rn(__fmul_rn(x, x), __fmul_rn(y, y)), __fmul_rn(z, z));
    ri[k] = vdw[t];
    cf[k] = (t == 0) ? 1.f : 0.f;
    nf[k] = (t == 1) ? 1.f : 0.f;
  }

  int cnt2 = 0, cnt1 = 0;  // wave-uniform after popcount(ballot)
  float pen = 0.f;
  const int j0 = jt * TJ;
#pragma unroll 4
  for (int jj = 0; jj < TJ; ++jj) {
    const int j = j0 + jj;
    const size_t jg = (size_t)b * A + j;  // uniform -> scalar loads
    const float sx = coords[jg * 3], sy = coords[jg * 3 + 1], sz = coords[jg * 3 + 2];
    const int st = types[jg];
    const float sr = vdw[st];
    const float sq = __fadd_rn(__fadd_rn(__fmul_rn(sx, sx), __fmul_rn(sy, sy)),
                               __fmul_rn(sz, sz));
    float dsq[NI];
#pragma unroll
    for (int k = 0; k < NI; ++k) {
      const float dot = fmaf(zi[k], sz, fmaf(yi[k], sy, xi[k] * sx));
      float d2 = fmaf(-2.f, dot, qi[k] + sq);
      d2 = fmaxf(d2, 1e-12f);
      dsq[k] = d2;
      const float mind = ri[k] + sr;
      const bool c = d2 < mind * mind;
      if (BAND) {
        cnt2 += __popcll(__ballot(c && (ii[k] < j)));
        cnt1 += __popcll(__ballot(c && (ii[k] == j)));
      } else {
        cnt2 += __popcll(__ballot(c));
      }
    }
    if (st <= 1) {  // j is C(0) or N(1): uniform branch, ~10.5% of j's
      const bool jn = (st == 1);
#pragma unroll
      for (int k = 0; k < NI; ++k) {
        const float dd = __builtin_amdgcn_sqrtf(dsq[k]);
        float pp = fmaxf(fabsf(dd - 1.33f) - 0.2f, 0.f);
        if (BAND) pp = (ii[k] < j) ? pp : 0.f;
        const float fl = jn ? cf[k] : nf[k];  // static index, cndmask select
        pen = fmaf(pp, fl, pen);
      }
    }
  }
  out_clash_wave = 2.f * cnt2 + (float)cnt1;  // wave-uniform
  out_pen = pen;                              // per-lane
}

__global__ __launch_bounds__(256) void fat_kernel(
    const float* __restrict__ rots_p, const float* __restrict__ trans_p,
    const float* __restrict__ coords_p,
    const float* __restrict__ rots_t, const float* __restrict__ trans_t,
    const float* __restrict__ coords_t,
    const int* __restrict__ types, const float* __restrict__ vdw,
    const float* __restrict__ res_mask, const float* __restrict__ mask,
    float* __restrict__ wsf, float* __restrict__ out, int R, int A) {
  const int tid = threadIdx.x;
  const int bid = blockIdx.x;
  __shared__ float sh_f[3][4];
  __shared__ double sh_d[5][4];
  __shared__ int sh_last;

  float* fape_part  = wsf + 4;
  float* clash_part = wsf + 4 + NB_FAPE;
  float* pen_part   = wsf + 4 + NB_FAPE + NB_PAIR;
  float* stats      = wsf + 4 + NB_FAPE + 2 * NB_PAIR;

  if (bid < NB_STAT) {
    // ---- stats blocks ----
    if (bid < 2) {
      const int b = bid;
      float c = 0.f, n = 0.f, ms = 0.f;
      for (int a = tid; a < A; a += 256) {
        const int t = types[(size_t)b * A + a];
        c += (t == 0) ? 1.f : 0.f;
        n += (t == 1) ? 1.f : 0.f;
        ms += mask[(size_t)b * A + a];
      }
      c = wred(c); n = wred(n); ms = wred(ms);
      if ((tid & 63) == 0) {
        const int w = tid >> 6;
        sh_f[0][w] = c; sh_f[1][w] = n; sh_f[2][w] = ms;
      }
      __syncthreads();
      if (tid == 0) {
        stats[b * 3 + 0] = sh_f[0][0] + sh_f[0][1] + sh_f[0][2] + sh_f[0][3];
        stats[b * 3 + 1] = sh_f[1][0] + sh_f[1][1] + sh_f[1][2] + sh_f[1][3];
        stats[b * 3 + 2] = sh_f[2][0] + sh_f[2][1] + sh_f[2][2] + sh_f[2][3];
      }
    } else {
      const int b = bid - 2;
      float rs = 0.f;
      for (int r = tid; r < R; r += 256) rs += res_mask[(size_t)b * R + r];
      rs = wred(rs);
      if ((tid & 63) == 0) sh_f[0][tid >> 6] = rs;
      __syncthreads();
      if (tid == 0) stats[6 + b] = sh_f[0][0] + sh_f[0][1] + sh_f[0][2] + sh_f[0][3];
    }
  } else {
    const int q = bid - NB_STAT;
    const int g7 = q / 7, r7 = q % 7;
    if (r7 < 2) {
      // ---- FAPE (atom-major) ----
      const int fbid = g7 * 2 + r7;     // [0,512)
      const int ag = fbid & 7;          // atom-group (1024 atoms, flat over B*A)
      const int rc = fbid >> 3;         // frame-chunk [0,64)
      const int b = ag >> 2;            // batch of this atom-group
      const int abase = ag * 1024;

      float ax[NA], ay[NA], az[NA], bx[NA], by[NA], bz[NA], am[NA], acc[NA];
#pragma unroll
      for (int k = 0; k < NA; ++k) {
        const size_t gx = (size_t)abase + tid + 256 * k;
        ax[k] = coords_p[gx * 3]; ay[k] = coords_p[gx * 3 + 1]; az[k] = coords_p[gx * 3 + 2];
        bx[k] = coords_t[gx * 3]; by[k] = coords_t[gx * 3 + 1]; bz[k] = coords_t[gx * 3 + 2];
        am[k] = mask[gx];
        acc[k] = 0.f;
      }

      const int fr0 = b * R + rc * RCH;
      for (int f = 0; f < RCH; ++f) {
        const size_t fr = (size_t)(fr0 + f);  // uniform -> s_load
        const float* Rp = rots_p + fr * 9;
        const float* Rt = rots_t + fr * 9;
        float rp[9], rt[9];
#pragma unroll
        for (int k2 = 0; k2 < 9; ++k2) { rp[k2] = Rp[k2]; rt[k2] = Rt[k2]; }
        const float tp0 = trans_p[fr * 3], tp1 = trans_p[fr * 3 + 1], tp2 = trans_p[fr * 3 + 2];
        const float tt0 = trans_t[fr * 3], tt1 = trans_t[fr * 3 + 1], tt2 = trans_t[fr * 3 + 2];
        const float rm = res_mask[fr];
        float cc[3];
#pragma unroll
        for (int i = 0; i < 3; ++i) {
          cc[i] = (rp[i] * tp0 + rp[3 + i] * tp1 + rp[6 + i] * tp2)
                - (rt[i] * tt0 + rt[3 + i] * tt1 + rt[6 + i] * tt2);
        }
#pragma unroll
        for (int k = 0; k < NA; ++k) {
          float u0 = fmaf(rp[0], ax[k], -cc[0]);
          u0 = fmaf(rp[3], ay[k], u0); u0 = fmaf(rp[6], az[k], u0);
          u0 = fmaf(-rt[0], bx[k], u0); u0 = fmaf(-rt[3], by[k], u0); u0 = fmaf(-rt[6], bz[k], u0);
          float u1 = fmaf(rp[1], ax[k], -cc[1]);
          u1 = fmaf(rp[4], ay[k], u1); u1 = fmaf(rp[7], az[k], u1);
          u1 = fmaf(-rt[1], bx[k], u1); u1 = fmaf(-rt[4], by[k], u1); u1 = fmaf(-rt[7], bz[k], u1);
          float u2 = fmaf(rp[2], ax[k], -cc[2]);
          u2 = fmaf(rp[5], ay[k], u2); u2 = fmaf(rp[8], az[k], u2);
          u2 = fmaf(-rt[2], bx[k], u2); u2 = fmaf(-rt[5], by[k], u2); u2 = fmaf(-rt[8], bz[k], u2);
          float e2 = fmaf(u0, u0, 1e-8f);
          e2 = fmaf(u1, u1, e2);
          e2 = fmaf(u2, u2, e2);
          const float e = fminf(__builtin_amdgcn_sqrtf(e2), 10.f);
          acc[k] = fmaf(e, rm, acc[k]);  // res_mask folded into accumulate
        }
      }
      float tot = 0.f;
#pragma unroll
      for (int k = 0; k < NA; ++k) tot = fmaf(acc[k], am[k], tot);  // mask hoisted
      tot = wred(tot);
      if ((tid & 63) == 0) sh_f[0][tid >> 6] = tot;
      __syncthreads();
      if (tid == 0) fape_part[fbid] = sh_f[0][0] + sh_f[0][1] + sh_f[0][2] + sh_f[0][3];
    } else {
      // ---- pair ----
      const int pbid = g7 * 5 + (r7 - 2);  // [0,1280)
      int b, ic, jt;
      bool band;
      if (pbid < NB_BAND) {
        band = true;
        b = pbid >> 8;
        const int r = pbid & 255;
        ic = r >> 6;
        jt = (ic << 6) + (r & 63);
      } else {
        const int q2 = pbid - NB_BAND;
        band = false;
        b = q2 / 384;
        const int r = q2 % 384;
        if (r < 192)      { ic = 0; jt = 64 + r; }
        else if (r < 320) { ic = 1; jt = 128 + (r - 192); }
        else              { ic = 2; jt = 192 + (r - 320); }
      }
      float oc, op;
      if (band) pair_body<true >(coords_p, types, vdw, A, b, ic, jt, tid, oc, op);
      else      pair_body<false>(coords_p, types, vdw, A, b, ic, jt, tid, oc, op);
      const float rpn = wred(op);
      if ((tid & 63) == 0) { sh_f[0][tid >> 6] = oc; sh_f[1][tid >> 6] = rpn; }
      __syncthreads();
      if (tid == 0) {
        clash_part[pbid] = sh_f[0][0] + sh_f[0][1] + sh_f[0][2] + sh_f[0][3];
        pen_part[pbid]   = sh_f[1][0] + sh_f[1][1] + sh_f[1][2] + sh_f[1][3];
      }
    }
  }

  // ---- ticket: last finished block finalizes ----
  __threadfence();
  if (tid == 0) {
    const unsigned old = atomicAdd((unsigned*)wsf, 1u);
    sh_last = (old == (unsigned)(NB_TOT - 1)) ? 1 : 0;
  }
  __syncthreads();
  if (!sh_last) return;
  __threadfence();  // acquire: all partials visible

  double sf = 0.0, c0 = 0.0, c1 = 0.0, p0 = 0.0, p1 = 0.0;
  for (int i = tid; i < NB_FAPE; i += 256) sf += (double)fape_part[i];
  for (int p = tid; p < NB_PAIR; p += 256) {
    const int bb2 = (p < NB_BAND) ? (p >> 8) : ((p - NB_BAND) / 384);
    const double cv = (double)clash_part[p];
    const double pv = (double)pen_part[p];
    if (bb2 == 0) { c0 += cv; p0 += pv; } else { c1 += cv; p1 += pv; }
  }
  double dv[5] = {sf, c0, c1, p0, p1};
#pragma unroll
  for (int k = 0; k < 5; ++k) {
    const double v = wredd(dv[k]);
    if ((tid & 63) == 0) sh_d[k][tid >> 6] = v;
  }
  __syncthreads();
  if (tid == 0) {
    double D[5];
#pragma unroll
    for (int k = 0; k < 5; ++k) D[k] = sh_d[k][0] + sh_d[k][1] + sh_d[k][2] + sh_d[k][3];
    const double msum = (double)stats[2] + (double)stats[5];
    const double rsum = (double)stats[6] + (double)stats[7];
    const double fape = D[0] / (msum * rsum + 1e-8);
    const double clash = (D[1] + D[2]) / (4.0 * (double)A);  // mean_b((cnt/2)/A), B=2
    const double np0 = fmax((double)stats[0] * (double)stats[1], 1.0);
    const double np1 = fmax((double)stats[3] * (double)stats[4], 1.0);
    const double phys = 0.5 * (D[3] / np0 + D[4] / np1);
    out[0] = (float)(fape + 0.05 * clash + 0.3 * phys);
  }
}

extern "C" void kernel_launch(void* const* d_in, const int* in_sizes, int n_in,
                              void* d_out, int out_size, void* d_ws, size_t ws_size,
                              hipStream_t stream) {
  const float* rots_p   = (const float*)d_in[0];
  const float* trans_p  = (const float*)d_in[1];
  const float* coords_p = (const float*)d_in[2];
  const float* rots_t   = (const float*)d_in[3];
  const float* trans_t  = (const float*)d_in[4];
  const float* coords_t = (const float*)d_in[5];
  const int*   types    = (const int*)d_in[6];
  const float* vdw      = (const float*)d_in[7];
  const float* res_mask = (const float*)d_in[8];
  const float* mask     = (const float*)d_in[9];
  float* out = (float*)d_out;

  const int R = in_sizes[8] / BB;  // 1024
  const int A = in_sizes[9] / BB;  // 4096

  hipMemsetAsync(d_ws, 0, 4, stream);  // zero the ticket counter
  fat_kernel<<<NB_TOT, 256, 0, stream>>>(
      rots_p, trans_p, coords_p, rots_t, trans_t, coords_t, types, vdw,
      res_mask, mask, (float*)d_ws, out, R, A);
}

// Round 9
// 96.606 us; speedup vs baseline: 2.0178x; 2.0178x over previous
//
#include <hip/hip_runtime.h>

// FAPELoss = fape + 0.05*clash + 0.3*physics -> single f32 scalar.
// Harness-fixed shapes: B=2, R=1024, A=4096, 19 vdw radii.
//
// TWO dispatches (R4 lesson: a 1796-block ticket+__threadfence finalize caused an
// L2-writeback storm -> 127us kernel; the second dispatch's implicit barrier is far
// cheaper than per-block device-scope release fences).
//   fat_kernel (2304 = 9*256 blocks): bid%9<4 -> FAPE (1024), bid%9>=4 -> pair (1280)
//   finalize_kernel (1 block x 1024 thr): partials + stats -> out[0]
//
// FAPE is ATOM-major: each thread keeps NA=4 atoms in VGPRs for its whole life and
// streams RCH=8 frames; frame scalars (22/frame) are wave-uniform -> s_load broadcast.
// Fully-unrolled frame loop lets the compiler hoist independent s_loads.
// mask hoisted to the per-atom epilogue; res_mask folded into the accumulate fma.
// Pair: no LDS (j is wave-uniform -> scalar loads); clash counted via
// __popcll(__ballot(c)) -> SALU, no per-lane accumulation, no clash shuffle-reduce.
// Pair symmetry: each unordered pair evaluated once (band blocks weight i<j / i==j);
// pen adds both ordered CN terms via the uniform j-class select.
// (d > EPS) is vacuous: d >= sqrt(1e-12) = 1e-6 > 1e-8. Clash cmp uses d2 < mind^2.
//
// ws floats: fape_part[1024] @0 | clash_part[1280] @1024 | pen_part[1280] @2304
// (every entry written unconditionally by its block -> no memset needed)

constexpr int BB = 2;

constexpr int NA = 4;         // atoms per thread (FAPE)
constexpr int RCH = 8;        // frames per FAPE block
constexpr int NB_FAPE = 1024; // 8 atom-groups x 128 frame-chunks

constexpr int NI = 4;     // i-atoms per thread (pair)
constexpr int TJ = 16;    // j-tile
constexpr int IC = 1024;  // i-chunk
constexpr int NB_BAND = 512;
constexpr int NB_FULL = 768;
constexpr int NB_PAIR = NB_BAND + NB_FULL;
constexpr int NB_TOT = NB_FAPE + NB_PAIR;  // 2304 = 9*256

__device__ __forceinline__ float wred(float v) {
#pragma unroll
  for (int o = 32; o > 0; o >>= 1) v += __shfl_down(v, o, 64);
  return v;
}
__device__ __forceinline__ double wredd(double v) {
#pragma unroll
  for (int o = 32; o > 0; o >>= 1) v += __shfl_down(v, o, 64);
  return v;
}

template <bool BAND>
__device__ __forceinline__ void pair_body(
    const float* __restrict__ coords, const int* __restrict__ types,
    const float* __restrict__ vdw, int A, int b, int ic, int jt, int tid,
    float& out_clash_wave, float& out_pen) {
  const int ibase = ic * IC;
  float xi[NI], yi[NI], zi[NI], qi[NI], ri[NI], cf[NI], nf[NI];
  int ii[NI];
#pragma unroll
  for (int k = 0; k < NI; ++k) {
    ii[k] = ibase + (k << 8) + tid;
    const size_t g = (size_t)b * A + ii[k];
    const float x = coords[g * 3], y = coords[g * 3 + 1], z = coords[g * 3 + 2];
    const int t = types[g];
    xi[k] = x; yi[k] = y; zi[k] = z;
    // match reference sq = ((x*x + y*y) + z*z) without fma contraction
    qi[k] = __fadd_rn(__fadd_rn(__fmul_rn(x, x), __fmul_rn(y, y)), __fmul_rn(z, z));
    ri[k] = vdw[t];
    cf[k] = (t == 0) ? 1.f : 0.f;
    nf[k] = (t == 1) ? 1.f : 0.f;
  }

  int cnt2 = 0, cnt1 = 0;  // wave-uniform after popcount(ballot)
  float pen = 0.f;
  const int j0 = jt * TJ;
#pragma unroll 4
  for (int jj = 0; jj < TJ; ++jj) {
    const int j = j0 + jj;
    const size_t jg = (size_t)b * A + j;  // uniform -> scalar loads
    const float sx = coords[jg * 3], sy = coords[jg * 3 + 1], sz = coords[jg * 3 + 2];
    const int st = types[jg];
    const float sr = vdw[st];
    const float sq = __fadd_rn(__fadd_rn(__fmul_rn(sx, sx), __fmul_rn(sy, sy)),
                               __fmul_rn(sz, sz));
    float dsq[NI];
#pragma unroll
    for (int k = 0; k < NI; ++k) {
      const float dot = fmaf(zi[k], sz, fmaf(yi[k], sy, xi[k] * sx));
      float d2 = fmaf(-2.f, dot, qi[k] + sq);
      d2 = fmaxf(d2, 1e-12f);
      dsq[k] = d2;
      const float mind = ri[k] + sr;
      const bool c = d2 < mind * mind;
      if (BAND) {
        cnt2 += __popcll(__ballot(c && (ii[k] < j)));
        cnt1 += __popcll(__ballot(c && (ii[k] == j)));
      } else {
        cnt2 += __popcll(__ballot(c));
      }
    }
    if (st <= 1) {  // j is C(0) or N(1): uniform branch, ~10.5% of j's
      const bool jn = (st == 1);
#pragma unroll
      for (int k = 0; k < NI; ++k) {
        const float dd = __builtin_amdgcn_sqrtf(dsq[k]);
        float pp = fmaxf(fabsf(dd - 1.33f) - 0.2f, 0.f);
        if (BAND) pp = (ii[k] < j) ? pp : 0.f;
        const float fl = jn ? cf[k] : nf[k];  // static index, cndmask select
        pen = fmaf(pp, fl, pen);
      }
    }
  }
  out_clash_wave = 2.f * cnt2 + (float)cnt1;  // wave-uniform
  out_pen = pen;                              // per-lane
}

__global__ __launch_bounds__(256) void fat_kernel(
    const float* __restrict__ rots_p, const float* __restrict__ trans_p,
    const float* __restrict__ coords_p,
    const float* __restrict__ rots_t, const float* __restrict__ trans_t,
    const float* __restrict__ coords_t,
    const int* __restrict__ types, const float* __restrict__ vdw,
    const float* __restrict__ res_mask, const float* __restrict__ mask,
    float* __restrict__ wsf, int R, int A) {
  const int tid = threadIdx.x;
  const int bid = blockIdx.x;
  const int g9 = bid / 9;
  const int r9 = bid % 9;
  __shared__ float sh_f[2][4];

  float* fape_part  = wsf;
  float* clash_part = wsf + NB_FAPE;
  float* pen_part   = wsf + NB_FAPE + NB_PAIR;

  if (r9 < 4) {
    // ---- FAPE (atom-major) ----
    const int fbid = g9 * 4 + r9;  // [0,1024)
    const int ag = fbid & 7;       // atom-group (1024 atoms, flat over B*A)
    const int rc = fbid >> 3;      // frame-chunk [0,128)
    const int b = ag >> 2;
    const int abase = ag * 1024;

    float ax[NA], ay[NA], az[NA], bx[NA], by[NA], bz[NA], am[NA], acc[NA];
#pragma unroll
    for (int k = 0; k < NA; ++k) {
      const size_t gx = (size_t)abase + tid + 256 * k;
      ax[k] = coords_p[gx * 3]; ay[k] = coords_p[gx * 3 + 1]; az[k] = coords_p[gx * 3 + 2];
      bx[k] = coords_t[gx * 3]; by[k] = coords_t[gx * 3 + 1]; bz[k] = coords_t[gx * 3 + 2];
      am[k] = mask[gx];
      acc[k] = 0.f;
    }

    const int fr0 = b * R + rc * RCH;
#pragma unroll
    for (int f = 0; f < RCH; ++f) {
      const size_t fr = (size_t)(fr0 + f);  // uniform -> s_load broadcast
      const float* Rp = rots_p + fr * 9;
      const float* Rt = rots_t + fr * 9;
      float rp[9], rt[9];
#pragma unroll
      for (int k2 = 0; k2 < 9; ++k2) { rp[k2] = Rp[k2]; rt[k2] = Rt[k2]; }
      const float tp0 = trans_p[fr * 3], tp1 = trans_p[fr * 3 + 1], tp2 = trans_p[fr * 3 + 2];
      const float tt0 = trans_t[fr * 3], tt1 = trans_t[fr * 3 + 1], tt2 = trans_t[fr * 3 + 2];
      const float rm = res_mask[fr];
      float cc[3];
#pragma unroll
      for (int i = 0; i < 3; ++i) {
        cc[i] = (rp[i] * tp0 + rp[3 + i] * tp1 + rp[6 + i] * tp2)
              - (rt[i] * tt0 + rt[3 + i] * tt1 + rt[6 + i] * tt2);
      }
#pragma unroll
      for (int k = 0; k < NA; ++k) {
        float u0 = fmaf(rp[0], ax[k], -cc[0]);
        u0 = fmaf(rp[3], ay[k], u0); u0 = fmaf(rp[6], az[k], u0);
        u0 = fmaf(-rt[0], bx[k], u0); u0 = fmaf(-rt[3], by[k], u0); u0 = fmaf(-rt[6], bz[k], u0);
        float u1 = fmaf(rp[1], ax[k], -cc[1]);
        u1 = fmaf(rp[4], ay[k], u1); u1 = fmaf(rp[7], az[k], u1);
        u1 = fmaf(-rt[1], bx[k], u1); u1 = fmaf(-rt[4], by[k], u1); u1 = fmaf(-rt[7], bz[k], u1);
        float u2 = fmaf(rp[2], ax[k], -cc[2]);
        u2 = fmaf(rp[5], ay[k], u2); u2 = fmaf(rp[8], az[k], u2);
        u2 = fmaf(-rt[2], bx[k], u2); u2 = fmaf(-rt[5], by[k], u2); u2 = fmaf(-rt[8], bz[k], u2);
        float e2 = fmaf(u0, u0, 1e-8f);
        e2 = fmaf(u1, u1, e2);
        e2 = fmaf(u2, u2, e2);
        const float e = fminf(__builtin_amdgcn_sqrtf(e2), 10.f);
        acc[k] = fmaf(e, rm, acc[k]);  // res_mask folded into accumulate
      }
    }
    float tot = 0.f;
#pragma unroll
    for (int k = 0; k < NA; ++k) tot = fmaf(acc[k], am[k], tot);  // mask hoisted
    tot = wred(tot);
    if ((tid & 63) == 0) sh_f[0][tid >> 6] = tot;
    __syncthreads();
    if (tid == 0) fape_part[fbid] = sh_f[0][0] + sh_f[0][1] + sh_f[0][2] + sh_f[0][3];
    return;
  }

  // ---- pair ----
  const int pbid = g9 * 5 + (r9 - 4);  // [0,1280)
  int b, ic, jt;
  bool band;
  if (pbid < NB_BAND) {
    band = true;
    b = pbid >> 8;
    const int r = pbid & 255;
    ic = r >> 6;
    jt = (ic << 6) + (r & 63);  // band: 64*ic <= jt < 64*(ic+1)
  } else {
    const int q2 = pbid - NB_BAND;
    band = false;
    b = q2 / 384;
    const int r = q2 % 384;
    if (r < 192)      { ic = 0; jt = 64 + r; }
    else if (r < 320) { ic = 1; jt = 128 + (r - 192); }
    else              { ic = 2; jt = 192 + (r - 320); }
  }
  float oc, op;
  if (band) pair_body<true >(coords_p, types, vdw, A, b, ic, jt, tid, oc, op);
  else      pair_body<false>(coords_p, types, vdw, A, b, ic, jt, tid, oc, op);
  const float rpn = wred(op);
  if ((tid & 63) == 0) { sh_f[0][tid >> 6] = oc; sh_f[1][tid >> 6] = rpn; }
  __syncthreads();
  if (tid == 0) {
    // oc is wave-uniform (ballot count): sum the 4 wave values directly
    clash_part[pbid] = sh_f[0][0] + sh_f[0][1] + sh_f[0][2] + sh_f[0][3];
    pen_part[pbid]   = sh_f[1][0] + sh_f[1][1] + sh_f[1][2] + sh_f[1][3];
  }
}

// ---------------- finalize (1 block x 1024 threads) -----------------------------
__global__ __launch_bounds__(1024) void finalize_kernel(
    const int* __restrict__ types, const float* __restrict__ res_mask,
    const float* __restrict__ mask, const float* __restrict__ wsf,
    float* __restrict__ out, int R, int A) {
  const int tid = threadIdx.x;
  const float* fape_part  = wsf;
  const float* clash_part = wsf + NB_FAPE;
  const float* pen_part   = wsf + NB_FAPE + NB_PAIR;

  double sf = 0.0, c0 = 0.0, c1 = 0.0, p0 = 0.0, p1 = 0.0;
  for (int i = tid; i < NB_FAPE; i += 1024) sf += (double)fape_part[i];
  for (int p = tid; p < NB_PAIR; p += 1024) {
    const int bb2 = (p < NB_BAND) ? (p >> 8) : ((p - NB_BAND) / 384);
    const double cv = (double)clash_part[p];
    const double pv = (double)pen_part[p];
    if (bb2 == 0) { c0 += cv; p0 += pv; } else { c1 += cv; p1 += pv; }
  }
  float cc0 = 0, cn0 = 0, cc1 = 0, cn1 = 0, sm = 0, srm = 0;
  for (int a = tid; a < A; a += 1024) {
    const int t0 = types[a], t1 = types[A + a];
    cc0 += (t0 == 0) ? 1.f : 0.f;
    cn0 += (t0 == 1) ? 1.f : 0.f;
    cc1 += (t1 == 0) ? 1.f : 0.f;
    cn1 += (t1 == 1) ? 1.f : 0.f;
    sm += mask[a] + mask[A + a];
  }
  for (int r = tid; r < R; r += 1024) srm += res_mask[r] + res_mask[R + r];

  __shared__ double dred[5][16];
  __shared__ float fred[6][16];
  double dv[5] = {sf, c0, c1, p0, p1};
  float fv[6] = {cc0, cn0, cc1, cn1, sm, srm};
#pragma unroll
  for (int k = 0; k < 5; ++k) {
    const double v = wredd(dv[k]);
    if ((tid & 63) == 0) dred[k][tid >> 6] = v;
  }
#pragma unroll
  for (int k = 0; k < 6; ++k) {
    const float v = wred(fv[k]);
    if ((tid & 63) == 0) fred[k][tid >> 6] = v;
  }
  __syncthreads();
  if (tid == 0) {
    double D[5];
    float F[6];
#pragma unroll
    for (int k = 0; k < 5; ++k) {
      double s = 0.0;
#pragma unroll
      for (int w = 0; w < 16; ++w) s += dred[k][w];
      D[k] = s;
    }
#pragma unroll
    for (int k = 0; k < 6; ++k) {
      float s = 0.f;
#pragma unroll
      for (int w = 0; w < 16; ++w) s += fred[k][w];
      F[k] = s;
    }
    const double fape = D[0] / ((double)F[4] * (double)F[5] + 1e-8);
    const double clash = (D[1] + D[2]) / (4.0 * (double)A);  // mean_b((cnt/2)/A), B=2
    const double np0 = fmax((double)F[0] * (double)F[1], 1.0);
    const double np1 = fmax((double)F[2] * (double)F[3], 1.0);
    const double phys = 0.5 * (D[3] / np0 + D[4] / np1);
    out[0] = (float)(fape + 0.05 * clash + 0.3 * phys);
  }
}

extern "C" void kernel_launch(void* const* d_in, const int* in_sizes, int n_in,
                              void* d_out, int out_size, void* d_ws, size_t ws_size,
                              hipStream_t stream) {
  const float* rots_p   = (const float*)d_in[0];
  const float* trans_p  = (const float*)d_in[1];
  const float* coords_p = (const float*)d_in[2];
  const float* rots_t   = (const float*)d_in[3];
  const float* trans_t  = (const float*)d_in[4];
  const float* coords_t = (const float*)d_in[5];
  const int*   types    = (const int*)d_in[6];
  const float* vdw      = (const float*)d_in[7];
  const float* res_mask = (const float*)d_in[8];
  const float* mask     = (const float*)d_in[9];
  float* out = (float*)d_out;

  const int R = in_sizes[8] / BB;  // 1024
  const int A = in_sizes[9] / BB;  // 4096

  fat_kernel<<<NB_TOT, 256, 0, stream>>>(
      rots_p, trans_p, coords_p, rots_t, trans_t, coords_t, types, vdw,
      res_mask, mask, (float*)d_ws, R, A);

  finalize_kernel<<<1, 1024, 0, stream>>>(
      types, res_mask, mask, (const float*)d_ws, out, R, A);
}